// Round 1
// baseline (88.841 us; speedup 1.0000x reference)
//
#include <hip/hip_runtime.h>

// Involution (RedNet-style), N=4 C=256 H=W=56, K=7, G=16, ratio=4 (Cr=64).
// k1: t[o][px] = relu(BN(x·w1^T + b1))          (o=0..63, px = n*3136+h*56+w)
// k2: fused  ker = t·w2^T + b2  (never materialized)  +  involution gather.

namespace {
constexpr int Nn  = 4;
constexpr int Cc  = 256;
constexpr int Hh  = 56;
constexpr int Ww  = 56;
constexpr int HW  = Hh * Ww;        // 3136
constexpr int NPX = Nn * HW;        // 12544
constexpr int KK  = 49;             // 7x7
}

// ---------------------------------------------------------------------------
// Kernel 1: 1x1 conv + BatchNorm(inference) + ReLU
// grid (196, 2) x 256 threads. lane = pixel, wave covers 8 output channels.
// t layout: [64][12544]  (coalesced stores here, coalesced loads in k2)
// ---------------------------------------------------------------------------
extern "C" __global__ void __launch_bounds__(256, 4)
k1_conv_bn_relu(const float* __restrict__ x,  const float* __restrict__ w1,
                const float* __restrict__ b1, const float* __restrict__ gamma,
                const float* __restrict__ beta, const float* __restrict__ mean,
                const float* __restrict__ var,  float* __restrict__ t)
{
    const int lane = threadIdx.x & 63;
    const int wv   = threadIdx.x >> 6;                       // 0..3
    const int px   = blockIdx.x * 64 + lane;                 // 0..12543 (exact)
    // wave-uniform output-channel base; readfirstlane => scalar w1 loads
    const int o0   = __builtin_amdgcn_readfirstlane((int)blockIdx.y * 32 + wv * 8);

    const int n  = px / HW;
    const int hw = px - n * HW;
    const float* xb = x + (size_t)n * Cc * HW + hw;

    float acc[8];
#pragma unroll
    for (int i = 0; i < 8; ++i) acc[i] = 0.f;

#pragma unroll 4
    for (int c = 0; c < Cc; ++c) {
        const float xv = xb[(size_t)c * HW];                 // coalesced across lanes
#pragma unroll
        for (int oo = 0; oo < 8; ++oo)
            acc[oo] = fmaf(xv, w1[(o0 + oo) * Cc + c], acc[oo]);  // uniform -> s_load
    }

#pragma unroll
    for (int oo = 0; oo < 8; ++oo) {
        const int o = o0 + oo;
        const float inv = rsqrtf(var[o] + 1e-5f);
        const float sc  = gamma[o] * inv;
        const float sh  = fmaf(b1[o] - mean[o], sc, beta[o]);
        float v = fmaf(acc[oo], sc, sh);
        t[(size_t)o * NPX + px] = v > 0.f ? v : 0.f;         // coalesced store
    }
}

// ---------------------------------------------------------------------------
// Kernel 2: fused kernel-generation GEMM (per-pixel 64-dot per tap) + involution
// grid (224, 4) x 256 threads. block = (n,h) row; wave = one group g; lane = w.
// Per lane: t[0..63] in registers; per tap k: kerk = <t, w2_row> + b2,
// then acc[c] += x[g*16+c, hh, ww] * kerk  for the 16 channels of the group.
// OOB kh rows skipped entirely (zero patches kill those taps).
// ---------------------------------------------------------------------------
extern "C" __global__ void __launch_bounds__(256, 2)
k2_involution(const float* __restrict__ x,  const float* __restrict__ t,
              const float* __restrict__ w2, const float* __restrict__ b2,
              float* __restrict__ out)
{
    const int lane = threadIdx.x & 63;                       // pixel w (0..55 active)
    const int wv   = threadIdx.x >> 6;                       // 0..3
    const int nh   = blockIdx.x;                             // n*56 + h
    const int n    = nh / Hh;
    const int h    = nh - n * Hh;
    const int g    = __builtin_amdgcn_readfirstlane((int)blockIdx.y * 4 + wv);
    const int wcl  = lane < Ww ? lane : (Ww - 1);            // clamp for safe t loads
    const int pxb  = nh * Ww;                                // n*3136 + h*56

    // t fragment for this pixel: 64 floats in registers (coalesced across lanes)
    float treg[64];
#pragma unroll
    for (int o = 0; o < 64; ++o)
        treg[o] = t[o * NPX + pxb + wcl];

    float acc[16];
#pragma unroll
    for (int i = 0; i < 16; ++i) acc[i] = 0.f;

    const float* xg  = x  + (size_t)n * Cc * HW + (size_t)(g * 16) * HW;
    const float* w2g = w2 + g * KK * 64;
    const float* b2g = b2 + g * KK;

    for (int kh = 0; kh < 7; ++kh) {
        const int hh = h + kh - 3;
        if (hh < 0 || hh >= Hh) continue;                    // uniform skip
        const float* xrow = xg + hh * Ww;
#pragma unroll
        for (int kw = 0; kw < 7; ++kw) {
            const int k = kh * 7 + kw;
            const float* w2row = w2g + k * 64;               // wave-uniform
            float p0 = 0.f, p1 = 0.f, p2 = 0.f, p3 = 0.f;
#pragma unroll
            for (int o = 0; o < 64; o += 4) {                // 64-FMA dot, 4 chains
                p0 = fmaf(treg[o + 0], w2row[o + 0], p0);
                p1 = fmaf(treg[o + 1], w2row[o + 1], p1);
                p2 = fmaf(treg[o + 2], w2row[o + 2], p2);
                p3 = fmaf(treg[o + 3], w2row[o + 3], p3);
            }
            const float kerk = ((p0 + p1) + (p2 + p3)) + b2g[k];
            const int ww = lane + kw - 3;
            if (ww >= 0 && ww < Ww) {                        // per-lane mask
#pragma unroll
                for (int c = 0; c < 16; ++c)
                    acc[c] = fmaf(xrow[(size_t)c * HW + ww], kerk, acc[c]);
            }
        }
    }

    if (lane < Ww) {
        float* og = out + (size_t)n * Cc * HW + (size_t)(g * 16) * HW + h * Ww + lane;
#pragma unroll
        for (int c = 0; c < 16; ++c)
            og[c * HW] = acc[c];                             // coalesced per c
    }
}

// ---------------------------------------------------------------------------
extern "C" void kernel_launch(void* const* d_in, const int* in_sizes, int n_in,
                              void* d_out, int out_size, void* d_ws, size_t ws_size,
                              hipStream_t stream)
{
    const float* x     = (const float*)d_in[0];
    const float* w1    = (const float*)d_in[1];
    const float* b1    = (const float*)d_in[2];
    const float* gamma = (const float*)d_in[3];
    const float* beta  = (const float*)d_in[4];
    const float* mean  = (const float*)d_in[5];
    const float* var   = (const float*)d_in[6];
    const float* w2    = (const float*)d_in[7];
    const float* b2    = (const float*)d_in[8];

    float* t   = (float*)d_ws;        // 64 * 12544 floats = 3.2 MB scratch
    float* out = (float*)d_out;

    k1_conv_bn_relu<<<dim3(NPX / 64, 2), 256, 0, stream>>>(
        x, w1, b1, gamma, beta, mean, var, t);
    k2_involution<<<dim3(Nn * Hh, 4), 256, 0, stream>>>(
        x, t, w2, b2, out);
}

// Round 3
// 83.373 us; speedup vs baseline: 1.0656x; 1.0656x over previous
//
#include <hip/hip_runtime.h>

// Involution (RedNet-style), N=4 C=256 H=W=56, K=7, G=16, ratio=4 (Cr=64).
// k1: t[o][px] = relu(BN(x·w1^T + b1))          (o=0..63, px = n*3136+h*56+w)
// k2: fused  ker = t·w2^T + b2  (never materialized)  +  involution gather.
//     Taps split across 4 waves per block; treg pinned in VGPRs via asm.

namespace {
constexpr int Nn  = 4;
constexpr int Cc  = 256;
constexpr int Hh  = 56;
constexpr int Ww  = 56;
constexpr int HW  = Hh * Ww;        // 3136
constexpr int NPX = Nn * HW;        // 12544
constexpr int KK  = 49;             // 7x7
}

// ---------------------------------------------------------------------------
// Kernel 1: 1x1 conv + BatchNorm(inference) + ReLU
// grid (196, 4) x 256 threads. lane = pixel; (blockIdx.y, wave) pick a 4-wide
// output-channel chunk (16 chunks cover o=0..63). 3136 waves -> 12/CU.
// t layout: [64][12544]  (coalesced stores here, coalesced loads in k2)
// ---------------------------------------------------------------------------
extern "C" __global__ void __launch_bounds__(256, 8)
k1_conv_bn_relu(const float* __restrict__ x,  const float* __restrict__ w1,
                const float* __restrict__ b1, const float* __restrict__ gamma,
                const float* __restrict__ beta, const float* __restrict__ mean,
                const float* __restrict__ var,  float* __restrict__ t)
{
    const int lane = threadIdx.x & 63;
    const int wv   = __builtin_amdgcn_readfirstlane(threadIdx.x >> 6);  // 0..3
    const int px   = blockIdx.x * 64 + lane;                 // 0..12543 (exact)
    const int o0   = __builtin_amdgcn_readfirstlane(((int)blockIdx.y * 4 + wv) * 4);

    const int n  = px / HW;
    const int hw = px - n * HW;
    const float* xb = x + (size_t)n * Cc * HW + hw;

    float a0 = 0.f, a1 = 0.f, a2 = 0.f, a3 = 0.f;

#pragma unroll 8
    for (int c = 0; c < Cc; ++c) {
        const float xv = xb[(size_t)c * HW];                 // coalesced across lanes
        a0 = fmaf(xv, w1[(o0 + 0) * Cc + c], a0);            // uniform -> s_load
        a1 = fmaf(xv, w1[(o0 + 1) * Cc + c], a1);
        a2 = fmaf(xv, w1[(o0 + 2) * Cc + c], a2);
        a3 = fmaf(xv, w1[(o0 + 3) * Cc + c], a3);
    }

    float accs[4] = {a0, a1, a2, a3};
#pragma unroll
    for (int oo = 0; oo < 4; ++oo) {
        const int o = o0 + oo;
        const float inv = rsqrtf(var[o] + 1e-5f);
        const float sc  = gamma[o] * inv;
        const float sh  = fmaf(b1[o] - mean[o], sc, beta[o]);
        float v = fmaf(accs[oo], sc, sh);
        t[(size_t)o * NPX + px] = v > 0.f ? v : 0.f;         // coalesced store
    }
}

// ---------------------------------------------------------------------------
// Kernel 2: fused kernel-generation dot + involution gather.
// grid (224 nh, 16 g) x 256 threads. block = (n,h) row & one group g.
// Wave wv handles taps k = wv, wv+4, ... (12-13 taps). Per tap:
//   kerk = <treg, w2_row> + b2   (treg = 64 t values, PINNED in VGPRs)
//   acc[c] += x[g*16+c, hh, ww] * kerk   (16 channels)
// Then 4-wave LDS reduction of acc[16] and one write per (c, w).
// 14336 waves -> 56/CU queued.
// ---------------------------------------------------------------------------
extern "C" __global__ void __launch_bounds__(256, 4)
k2_involution(const float* __restrict__ x,  const float* __restrict__ t,
              const float* __restrict__ w2, const float* __restrict__ b2,
              float* __restrict__ out)
{
    __shared__ float red[4][16][64];                         // 16 KB

    const int lane = threadIdx.x & 63;                       // pixel w (0..55 active)
    const int wv   = __builtin_amdgcn_readfirstlane(threadIdx.x >> 6);  // 0..3
    const int nh   = blockIdx.x;                             // n*56 + h
    const int n    = nh / Hh;
    const int h    = nh - n * Hh;
    const int g    = __builtin_amdgcn_readfirstlane((int)blockIdx.y);
    const int wcl  = lane < Ww ? lane : (Ww - 1);            // clamp for safe t loads
    const int pxb  = nh * Ww;                                // n*3136 + h*56

    // t fragment for this pixel: 64 floats, forced resident in VGPRs.
    float treg[64];
#pragma unroll
    for (int o = 0; o < 64; ++o)
        treg[o] = t[o * NPX + pxb + wcl];                    // coalesced
#pragma unroll
    for (int o = 0; o < 64; ++o)
        asm volatile("" : "+v"(treg[o]));                    // pin: no load re-sinking

    float acc[16];
#pragma unroll
    for (int i = 0; i < 16; ++i) acc[i] = 0.f;

    const float* xg  = x  + (size_t)n * Cc * HW + (size_t)(g * 16) * HW;
    const float* w2g = w2 + g * KK * 64;
    const float* b2g = b2 + g * KK;

    for (int k = wv; k < KK; k += 4) {                       // tap split across waves
        const int kh = k / 7;
        const int kw = k - kh * 7;
        const int hh = h + kh - 3;
        if (hh < 0 || hh >= Hh) continue;                    // wave-uniform skip
        const float* xrow  = xg + hh * Ww;
        const float* w2row = w2g + k * 64;                   // wave-uniform -> s_load
        float p0 = 0.f, p1 = 0.f, p2 = 0.f, p3 = 0.f;
#pragma unroll
        for (int o = 0; o < 64; o += 4) {                    // 64-FMA dot, 4 chains
            p0 = fmaf(treg[o + 0], w2row[o + 0], p0);
            p1 = fmaf(treg[o + 1], w2row[o + 1], p1);
            p2 = fmaf(treg[o + 2], w2row[o + 2], p2);
            p3 = fmaf(treg[o + 3], w2row[o + 3], p3);
        }
        const float kerk = ((p0 + p1) + (p2 + p3)) + b2g[k];
        const int ww = lane + kw - 3;
        if (ww >= 0 && ww < Ww) {                            // per-lane mask
#pragma unroll
            for (int c = 0; c < 16; ++c)
                acc[c] = fmaf(xrow[(size_t)c * HW + ww], kerk, acc[c]);
        }
    }

    // ---- cross-wave reduction: red[wv][c][lane] ----
#pragma unroll
    for (int c = 0; c < 16; ++c)
        red[wv][c][lane] = acc[c];
    __syncthreads();

    if (lane < Ww) {
        float* og = out + (size_t)n * Cc * HW + (size_t)(g * 16) * HW + h * Ww + lane;
#pragma unroll
        for (int j = 0; j < 4; ++j) {
            const int c = wv * 4 + j;
            const float s = red[0][c][lane] + red[1][c][lane]
                          + red[2][c][lane] + red[3][c][lane];
            og[c * HW] = s;                                  // coalesced per c
        }
    }
}

// ---------------------------------------------------------------------------
extern "C" void kernel_launch(void* const* d_in, const int* in_sizes, int n_in,
                              void* d_out, int out_size, void* d_ws, size_t ws_size,
                              hipStream_t stream)
{
    const float* x     = (const float*)d_in[0];
    const float* w1    = (const float*)d_in[1];
    const float* b1    = (const float*)d_in[2];
    const float* gamma = (const float*)d_in[3];
    const float* beta  = (const float*)d_in[4];
    const float* mean  = (const float*)d_in[5];
    const float* var   = (const float*)d_in[6];
    const float* w2    = (const float*)d_in[7];
    const float* b2    = (const float*)d_in[8];

    float* t   = (float*)d_ws;        // 64 * 12544 floats = 3.2 MB scratch
    float* out = (float*)d_out;

    k1_conv_bn_relu<<<dim3(NPX / 64, 4), 256, 0, stream>>>(
        x, w1, b1, gamma, beta, mean, var, t);
    k2_involution<<<dim3(Nn * Hh, 16), 256, 0, stream>>>(
        x, t, w2, b2, out);
}